// Round 9
// baseline (165.083 us; speedup 1.0000x reference)
//
#include <hip/hip_runtime.h>
#include <stdint.h>
#include <stddef.h>

// ---- problem constants ----
#define K_CODES 1024
#define D_DIM   256
#define HW      1024      // 32*32 spatial
#define N_VEC   32768
#define TOT_ELEMS 8388608

typedef float    v4f __attribute__((ext_vector_type(4)));
typedef _Float16 v8h __attribute__((ext_vector_type(8)));

// ------------------------------------------------------------------
// K1: codebook -> fp16 copy + 0.5*||e||^2
__global__ void prep_emb(const float* __restrict__ emb,
                         _Float16* __restrict__ emb_h,
                         float* __restrict__ hnorm) {
    int k = blockIdx.x, t = threadIdx.x;
    float v = emb[(size_t)k * D_DIM + t];
    emb_h[(size_t)k * D_DIM + t] = (_Float16)v;
    float s = v * v;
    for (int off = 32; off; off >>= 1) s += __shfl_down(s, off);
    __shared__ float wsum[4];
    if ((t & 63) == 0) wsum[t >> 6] = s;
    __syncthreads();
    if (t == 0) hnorm[k] = 0.5f * (wsum[0] + wsum[1] + wsum[2] + wsum[3]);
}

// ------------------------------------------------------------------
// K2: fused VQ, NO LDS staging / NO K-loop barriers (r4-r8 post-mortem:
// every barrier-windowed LDS variant plateaus at 50-66 us).
// Grid 512 x 256 thr: 4 waves = 4 code-slices (256 codes each) over the
// SAME 64 rows. A-fragments: 64 rows resident in 128 VGPRs (cap 256 via
// launch_bounds(256,2); a 128 cap spills - r7). B-fragments streamed
// directly from L2 (emb_h 512 KB, resident in every XCD L2):
// 2048 waves x 128 KB = 256 MB @ 34.5 TB/s ~ 7.5 us floor.
// dist' = 0.5||e||^2 - <z,e>;  loss_row = 2*min + ||z_row||^2.
__global__ __launch_bounds__(256, 2) void
vq_main(const float* __restrict__ z,
        const _Float16* __restrict__ emb_h,
        const float* __restrict__ emb,
        const float* __restrict__ hnorm,
        float* __restrict__ out,
        float* __restrict__ loss_acc) {
    __shared__ float  norm_s[K_CODES];   // 4 KB
    __shared__ float  rnorm_s[64];
    __shared__ float2 mrg[3][64];
    __shared__ int    idx_s[64];
    __shared__ __align__(16) float zq[64 * 257];  // 66 KB epilogue gather

    int t    = threadIdx.x;
    int wq   = t >> 6;        // code-slice 0..3 (one wave per SIMD)
    int lane = t & 63;
    int col  = lane & 15;
    int quad = lane >> 4;
    int b    = blockIdx.x >> 4;
    int hw0  = (blockIdx.x & 15) * 64;
    const float* zb = z + (size_t)b * D_DIM * HW;

    for (int i = t; i < K_CODES; i += 256) norm_s[i] = hnorm[i];

    // A fragments: 4 row-tiles x 8 D-chunks = 128 VGPRs, + fp32 row norms
    v8h   af[4][8];
    float zs[4] = {0.f, 0.f, 0.f, 0.f};
#pragma unroll
    for (int rt = 0; rt < 4; ++rt) {
#pragma unroll
        for (int c = 0; c < 8; ++c) {
#pragma unroll
            for (int j = 0; j < 8; ++j) {
                int d = c * 32 + quad * 8 + j;
                float v = zb[(size_t)d * HW + hw0 + rt * 16 + col];
                af[rt][c][j] = (_Float16)v;
                zs[rt] += v * v;
            }
        }
    }
    if (wq == 0) {
#pragma unroll
        for (int rt = 0; rt < 4; ++rt) {
            zs[rt] += __shfl_xor(zs[rt], 16);
            zs[rt] += __shfl_xor(zs[rt], 32);
        }
        if (quad == 0) {
#pragma unroll
            for (int rt = 0; rt < 4; ++rt) rnorm_s[rt * 16 + col] = zs[rt];
        }
    }
    __syncthreads();   // norm_s / rnorm_s ready

    float minv[16]; int mini[16];
#pragma unroll
    for (int r = 0; r < 16; ++r) { minv[r] = 3.4e38f; mini[r] = 0; }

    // K-loop: 16 iters x 16 codes, B straight from L2, zero barriers
    for (int it = 0; it < 16; ++it) {
        int code = wq * 256 + it * 16 + col;
        const v8h* bp = (const v8h*)(emb_h + (size_t)code * D_DIM);
        v8h bf[8];
#pragma unroll
        for (int c = 0; c < 8; ++c) bf[c] = bp[c * 4 + quad];
        v4f acc[4];
#pragma unroll
        for (int rt = 0; rt < 4; ++rt) acc[rt] = (v4f){0.f, 0.f, 0.f, 0.f};
#pragma unroll
        for (int c = 0; c < 8; ++c) {
#pragma unroll
            for (int rt = 0; rt < 4; ++rt)
                acc[rt] = __builtin_amdgcn_mfma_f32_16x16x32_f16(
                    af[rt][c], bf[c], acc[rt], 0, 0, 0);
        }
        float n = norm_s[code];
#pragma unroll
        for (int rt = 0; rt < 4; ++rt) {
#pragma unroll
            for (int r = 0; r < 4; ++r) {
                float d = n - acc[rt][r];
                if (d < minv[rt * 4 + r]) {
                    minv[rt * 4 + r] = d; mini[rt * 4 + r] = code;
                }
            }
        }
    }
    // reduce across the 16 cols of each quad (tie -> lower code idx)
#pragma unroll
    for (int off = 1; off < 16; off <<= 1) {
#pragma unroll
        for (int r = 0; r < 16; ++r) {
            float ov = __shfl_xor(minv[r], off);
            int   oi = __shfl_xor(mini[r], off);
            if (ov < minv[r] || (ov == minv[r] && oi < mini[r])) {
                minv[r] = ov; mini[r] = oi;
            }
        }
    }
    // slices 1..3 post; slice 0 merges (strict < keeps lowest slice/idx)
    if (wq >= 1 && col == 0) {
#pragma unroll
        for (int r = 0; r < 16; ++r) {
            int row = (r >> 2) * 16 + quad * 4 + (r & 3);
            mrg[wq - 1][row] = make_float2(minv[r], __int_as_float(mini[r]));
        }
    }
    __syncthreads();
    float lsum = 0.f;
    if (wq == 0 && col == 0) {
#pragma unroll
        for (int r = 0; r < 16; ++r) {
            int row = (r >> 2) * 16 + quad * 4 + (r & 3);
            float v = minv[r]; int mi = mini[r];
#pragma unroll
            for (int w = 0; w < 3; ++w) {
                float2 m2 = mrg[w][row];
                if (m2.x < v) { v = m2.x; mi = __float_as_int(m2.y); }
            }
            idx_s[row] = mi;
            lsum += 2.f * v + rnorm_s[row];
        }
    }
    if (wq == 0) {
        for (int off = 32; off; off >>= 1) lsum += __shfl_down(lsum, off);
        if (lane == 0) atomicAdd(loss_acc, lsum);
    }
    __syncthreads();

    // ---- epilogue: gather emb rows -> LDS (pad 257), coalesced store ----
#pragma unroll 4
    for (int row = 0; row < 64; ++row)
        zq[row * 257 + t] = emb[(size_t)idx_s[row] * D_DIM + t];
    __syncthreads();
#pragma unroll 4
    for (int p = 0; p < 64; ++p) {
        int d   = p * 4 + (t >> 6);
        int hwl = t & 63;
        out[(size_t)(b * D_DIM + d) * HW + hw0 + hwl] = zq[hwl * 257 + d];
    }
}

// ------------------------------------------------------------------
// K3: vq_loss = 1.25 * sum / TOT_ELEMS
__global__ void finalize(const float* __restrict__ loss_acc,
                         float* __restrict__ out_loss) {
    out_loss[0] = loss_acc[0] * (1.25f / (float)TOT_ELEMS);
}

// ------------------------------------------------------------------
extern "C" void kernel_launch(void* const* d_in, const int* in_sizes, int n_in,
                              void* d_out, int out_size, void* d_ws, size_t ws_size,
                              hipStream_t stream) {
    const float* z   = (const float*)d_in[0];   // [32,256,32,32]
    const float* emb = (const float*)d_in[1];   // [1024,256]
    float* out = (float*)d_out;                 // [8388608 z_q_st][1 loss]

    char* ws = (char*)d_ws;
    float*    loss_acc = (float*)ws;            // @0 (zeroed below)
    float*    hnorm    = (float*)(ws + 1024);   // 4 KB
    _Float16* emb_h    = (_Float16*)(ws + 8192);// 512 KB

    hipMemsetAsync(d_ws, 0, 256, stream);
    prep_emb<<<dim3(K_CODES), dim3(256), 0, stream>>>(emb, emb_h, hnorm);
    vq_main<<<dim3(512), dim3(256), 0, stream>>>(z, emb_h, emb, hnorm, out, loss_acc);
    finalize<<<dim3(1), dim3(1), 0, stream>>>(loss_acc, out + TOT_ELEMS);
}